// Round 5
// baseline (230.626 us; speedup 1.0000x reference)
//
#include <hip/hip_runtime.h>
#include <math.h>

// ---------- types / helpers ----------
typedef __attribute__((ext_vector_type(8))) short short8;
typedef __attribute__((ext_vector_type(4))) float f32x4;

__device__ __forceinline__ unsigned short f2bf(float f) {
  unsigned u = __float_as_uint(f);
  unsigned r = (u + 0x7FFFu + ((u >> 16) & 1u)) >> 16;
  return (unsigned short)r;
}

__device__ __forceinline__ void gload_lds16(const void* gsrc, void* ldst) {
  __builtin_amdgcn_global_load_lds(
      (__attribute__((address_space(1))) void*)(void*)(size_t)(const char*)gsrc,
      (__attribute__((address_space(3))) void*)ldst, 16, 0, 0);
}

#define WAIT_VM8 asm volatile("s_waitcnt vmcnt(8)" ::: "memory")
#define WAIT_VM0 asm volatile("s_waitcnt vmcnt(0)" ::: "memory")
#define WAIT_LGKM0 asm volatile("s_waitcnt lgkmcnt(0)" ::: "memory")
#define SBAR __builtin_amdgcn_s_barrier()
#define SCHED0 __builtin_amdgcn_sched_barrier(0)

// ---------- prep: bf16 converts (embed, post_w^T) ----------
__global__ __launch_bounds__(256) void prep_convert_kernel(
    const float* __restrict__ embed, const float* __restrict__ post_w,
    unsigned short* __restrict__ embedbf, unsigned short* __restrict__ pwtbf) {
  int id = blockIdx.x * 256 + threadIdx.x;
  if (id < 1048576) {
    embedbf[id] = f2bf(embed[id]);
  } else {
    int i = id - 1048576;   // pwt[j][d] = post_w[d][j]
    int j = i >> 10, dd = i & 1023;
    pwtbf[i] = f2bf(post_w[dd * 256 + j]);
  }
}

// ---------- e_sq[k], q[k]=pre_b.e_k, c0[k] ----------
__global__ __launch_bounds__(256) void esq_kernel(
    const float* __restrict__ embed, const float* __restrict__ pre_b,
    float* __restrict__ e_sq, float* __restrict__ qv, float* __restrict__ c0) {
  int t = threadIdx.x, l = t & 63, w = t >> 6;
  int k = blockIdx.x * 4 + w;
  const float* er = embed + (size_t)k * 1024;
  float s1 = 0.f, s2 = 0.f;
#pragma unroll
  for (int j = 0; j < 16; ++j) {
    float e = er[l + 64 * j];
    s1 += e * e;
    s2 += pre_b[l + 64 * j] * e;
  }
  for (int m = 32; m; m >>= 1) { s1 += __shfl_xor(s1, m); s2 += __shfl_xor(s2, m); }
  if (l == 0) { e_sq[k] = s1; qv[k] = s2; c0[k] = s1 - 2.0f * s2 - 1024.0f; }
}

// ---------- P[k][c] = sum_d embed[k,d] * pre_w[c,d]  (fp64 accum, 8-way ILP) ----------
__global__ __launch_bounds__(256) void pgemm_kernel(
    const float* __restrict__ embed, const float* __restrict__ pre_w,
    float* __restrict__ prow, unsigned short* __restrict__ prowbf) {
  __shared__ float Es[2][1024];
  const int t = threadIdx.x;
  const int k0 = blockIdx.x * 2;
#pragma unroll
  for (int i = 0; i < 2; ++i)
    *(float4*)(&Es[i][t * 4]) = *(const float4*)(embed + (size_t)(k0 + i) * 1024 + t * 4);
  __syncthreads();
  const float* wr = pre_w + (size_t)t * 1024;
  double a0 = 0, b0 = 0, c0_ = 0, d0 = 0;
  double a1 = 0, b1 = 0, c1 = 0, d1 = 0;
#pragma unroll 4
  for (int d = 0; d < 1024; d += 4) {
    float4 wv = *(const float4*)(wr + d);
    float4 e0 = *(const float4*)(&Es[0][d]);
    float4 e1 = *(const float4*)(&Es[1][d]);
    a0 += (double)wv.x * e0.x; b0 += (double)wv.y * e0.y;
    c0_ += (double)wv.z * e0.z; d0 += (double)wv.w * e0.w;
    a1 += (double)wv.x * e1.x; b1 += (double)wv.y * e1.y;
    c1 += (double)wv.z * e1.z; d1 += (double)wv.w * e1.w;
  }
  double s0 = (a0 + b0) + (c0_ + d0);
  double s1 = (a1 + b1) + (c1 + d1);
  float p0 = (float)s0, p1 = (float)s1;
  prow[(size_t)k0 * 256 + t] = p0;
  prow[(size_t)(k0 + 1) * 256 + t] = p1;
  prowbf[(size_t)k0 * 256 + t] = f2bf(p0);
  prowbf[(size_t)(k0 + 1) * 256 + t] = f2bf(p1);
}

// ---------- Q = pre_w @ pre_w^T (256x256, fp32->bf16), wb2 = 2*W.b, bsq=||b||^2 ----------
__global__ __launch_bounds__(256) void qmat_kernel(
    const float* __restrict__ pre_w, const float* __restrict__ pre_b,
    unsigned short* __restrict__ qbf, float* __restrict__ wbv) {
  __shared__ float Es[4][1024];
  __shared__ float red[4];
  const int t = threadIdx.x;
  if (blockIdx.x < 64) {
    const int a0 = blockIdx.x * 4;
#pragma unroll
    for (int i = 0; i < 4; ++i)
      *(float4*)(&Es[i][t * 4]) = *(const float4*)(pre_w + (size_t)(a0 + i) * 1024 + t * 4);
    __syncthreads();
    const float* wr = pre_w + (size_t)t * 1024;
    float acc[4] = {0.f, 0.f, 0.f, 0.f};
    for (int d = 0; d < 1024; d += 4) {
      float4 wv = *(const float4*)(wr + d);
#pragma unroll
      for (int q = 0; q < 4; ++q)
        acc[q] += wv.x * Es[q][d] + wv.y * Es[q][d + 1] + wv.z * Es[q][d + 2] + wv.w * Es[q][d + 3];
    }
#pragma unroll
    for (int q = 0; q < 4; ++q) qbf[(size_t)(a0 + q) * 256 + t] = f2bf(acc[q]);
  } else {
    const float* wr = pre_w + (size_t)t * 1024;
    float s = 0.f;
    for (int d = 0; d < 1024; d += 4) {
      float4 bv = *(const float4*)(pre_b + d);
      float4 wv = *(const float4*)(wr + d);
      s += wv.x * bv.x + wv.y * bv.y + wv.z * bv.z + wv.w * bv.w;
    }
    wbv[t] = 2.f * s;
    float4 bv = *(const float4*)(pre_b + t * 4);
    float sb = bv.x * bv.x + bv.y * bv.y + bv.z * bv.z + bv.w * bv.w;
    for (int m = 32; m; m >>= 1) sb += __shfl_xor(sb, m);
    if ((t & 63) == 0) red[t >> 6] = sb;
    __syncthreads();
    if (t == 0) wbv[256] = red[0] + red[1] + red[2] + red[3];
  }
}

// ---------- LN + GELU: g (f32) and g (bf16) ----------
__global__ __launch_bounds__(256) void lngelu_kernel(
    const float* __restrict__ x, const float* __restrict__ gamma,
    const float* __restrict__ beta, float* __restrict__ g,
    unsigned short* __restrict__ gbf) {
  int t = threadIdx.x, l = t & 63, w = t >> 6;
  int r = blockIdx.x * 4 + w;
  const float4 xv = *(const float4*)(x + (size_t)r * 256 + l * 4);
  float s = xv.x + xv.y + xv.z + xv.w;
  for (int m = 32; m; m >>= 1) s += __shfl_xor(s, m);
  const float mu = s * (1.0f / 256.0f);
  float dx = xv.x - mu, dy = xv.y - mu, dz = xv.z - mu, dw = xv.w - mu;
  float vs = dx * dx + dy * dy + dz * dz + dw * dw;
  for (int m = 32; m; m >>= 1) vs += __shfl_xor(vs, m);
  const float rstd = rsqrtf(vs * (1.0f / 256.0f) + 1e-5f);
  float4 gm = *(const float4*)(gamma + l * 4);
  float4 bt = *(const float4*)(beta + l * 4);
  float v0 = dx * rstd * gm.x + bt.x;
  float v1 = dy * rstd * gm.y + bt.y;
  float v2 = dz * rstd * gm.z + bt.z;
  float v3 = dw * rstd * gm.w + bt.w;
  const float is2 = 0.70710678118654752f;
  float4 o;
  o.x = 0.5f * v0 * (1.0f + erff(v0 * is2));
  o.y = 0.5f * v1 * (1.0f + erff(v1 * is2));
  o.z = 0.5f * v2 * (1.0f + erff(v2 * is2));
  o.w = 0.5f * v3 * (1.0f + erff(v3 * is2));
  *(float4*)(g + (size_t)r * 256 + l * 4) = o;
  ushort4 u;
  u.x = f2bf(o.x); u.y = f2bf(o.y); u.z = f2bf(o.z); u.w = f2bf(o.w);
  *(ushort4*)(gbf + (size_t)r * 256 + l * 4) = u;
}

// Swizzled stage: linear LDS dest, XOR-permuted global source slot; read side
// applies the same XOR. 8 global_load_lds per thread per tile.
__device__ __forceinline__ void stage_tile256(
    int t, const unsigned short* __restrict__ Asrc, size_t a_row_stride,
    const unsigned short* __restrict__ Bsrc, size_t b_row_stride, int k0,
    unsigned short* Ab, unsigned short* Bb) {
#pragma unroll
  for (int i = 0; i < 4; ++i) {
    int ca = t + 256 * i;
    int r = ca >> 3;
    int sp = (ca & 7) ^ (r & 7);
    gload_lds16(Asrc + (size_t)r * a_row_stride + k0 + sp * 8, (char*)Ab + ca * 16);
    gload_lds16(Bsrc + (size_t)r * b_row_stride + k0 + sp * 8, (char*)Bb + ca * 16);
  }
}

// Counted-vmcnt pipelined K-loop body shared by g1/zq/g2 via macro.
// Per iter: ds_read all frags -> lgkm0 -> barrier -> stage(kt+2) -> MFMA
// -> vmcnt(8 or 0) -> barrier. Loads span a full iteration.
#define PIPE_LOOP(NT, STAGE)                                                   \
  STAGE(0, 0);                                                                 \
  STAGE(1, 1);                                                                 \
  WAIT_VM8; SBAR; SCHED0;                                                      \
  for (int kt = 0; kt < (NT); ++kt) {                                          \
    const int cur = kt & 1;                                                    \
    const unsigned short* Ab = &lds[cur][0];                                   \
    const unsigned short* Bb = &lds[cur][8192];                                \
    short8 af[2][4], bq[2][4];                                                 \
    _Pragma("unroll")                                                          \
    for (int ks = 0; ks < 2; ++ks) {                                           \
      const int sp = ((ks << 2) + (l >> 4)) ^ (l & 7);                         \
      _Pragma("unroll")                                                        \
      for (int mi = 0; mi < 4; ++mi)                                           \
        af[ks][mi] = *(const short8*)(Ab + (wm + mi * 16 + (l & 15)) * 64 + sp * 8); \
      _Pragma("unroll")                                                        \
      for (int ni = 0; ni < 4; ++ni)                                           \
        bq[ks][ni] = *(const short8*)(Bb + (wn + ni * 16 + (l & 15)) * 64 + sp * 8); \
    }                                                                          \
    WAIT_LGKM0; SCHED0;                                                        \
    SBAR; SCHED0;                                                              \
    if (kt + 2 < (NT)) { STAGE(cur, kt + 2); }                                 \
    SCHED0;                                                                    \
    _Pragma("unroll")                                                          \
    for (int ks = 0; ks < 2; ++ks)                                             \
      _Pragma("unroll")                                                        \
      for (int mi = 0; mi < 4; ++mi)                                           \
        _Pragma("unroll")                                                      \
        for (int ni = 0; ni < 4; ++ni)                                         \
          acc[mi][ni] = __builtin_amdgcn_mfma_f32_16x16x32_bf16(af[ks][mi], bq[ks][ni], acc[mi][ni], 0, 0, 0); \
    if (kt + 1 < (NT)) {                                                       \
      if (kt + 2 < (NT)) { WAIT_VM8; } else { WAIT_VM0; }                      \
      SCHED0; SBAR; SCHED0;                                                    \
    }                                                                          \
  }

// ---------- G1: scores only. M=32768 N=1024 K=256 ----------
__global__ __launch_bounds__(256) void g1_kernel(
    const unsigned short* __restrict__ gbf,     // [32768][256]
    const unsigned short* __restrict__ prowbf,  // [1024][256]
    const float* __restrict__ c0,
    unsigned short* __restrict__ scores) {      // [32768][1024]
  __shared__ unsigned short lds[2][16384];
  const int t = threadIdx.x;
  const int bn = blockIdx.x;   // 0..7
  const int bm = blockIdx.y;   // 0..255
  const int m0 = bm * 128;
  const unsigned short* Bsrc = prowbf + bn * 128 * 256;
  f32x4 acc[4][4] = {};
  const int w = t >> 6, l = t & 63;
  const int wm = (w >> 1) * 64, wn = (w & 1) * 64;
#define G1_STAGE(buf, kt) stage_tile256(t, gbf + (size_t)m0 * 256, 256, Bsrc, 256, (kt) * 64, &lds[buf][0], &lds[buf][8192])
  PIPE_LOOP(4, G1_STAGE)
#undef G1_STAGE
  const int lrow = (l >> 4) * 4;
  const int lcol = l & 15;
  const int n0 = bn * 128;
#pragma unroll
  for (int mi = 0; mi < 4; ++mi)
#pragma unroll
    for (int ni = 0; ni < 4; ++ni) {
      int gcol = n0 + wn + ni * 16 + lcol;
      float cc = c0[gcol];
#pragma unroll
      for (int r = 0; r < 4; ++r) {
        int grow = m0 + wm + mi * 16 + lrow + r;
        scores[(size_t)grow * 1024 + gcol] = f2bf(cc - 2.0f * acc[mi][ni][r]);
      }
    }
}

// ---------- ZQ: z_sq via Q. gQ = G@Q (M=32768 N=256 K=256), z_sq=rowsum(gQ*G)+2g.wb+bsq ----------
__global__ __launch_bounds__(256) void zq_kernel(
    const unsigned short* __restrict__ gbf, const unsigned short* __restrict__ qbf,
    const float* __restrict__ g, const float* __restrict__ wbv,
    float* __restrict__ z_sq) {
  __shared__ unsigned short lds[2][16384];
  const int t = threadIdx.x;
  const int bn = blockIdx.x;  // 0..1
  const int bm = blockIdx.y;  // 0..255
  const int m0 = bm * 128;
  const unsigned short* Bsrc = qbf + bn * 128 * 256;
  f32x4 acc[4][4] = {};
  const int w = t >> 6, l = t & 63;
  const int wm = (w >> 1) * 64, wn = (w & 1) * 64;
#define ZQ_STAGE(buf, kt) stage_tile256(t, gbf + (size_t)m0 * 256, 256, Bsrc, 256, (kt) * 64, &lds[buf][0], &lds[buf][8192])
  PIPE_LOOP(4, ZQ_STAGE)
#undef ZQ_STAGE
  const int lrow = (l >> 4) * 4;
  const int lcol = l & 15;
  const float bsq = wbv[256];
#pragma unroll
  for (int mi = 0; mi < 4; ++mi)
#pragma unroll
    for (int r = 0; r < 4; ++r) {
      int grow = m0 + wm + mi * 16 + lrow + r;
      float v = 0.f;
#pragma unroll
      for (int ni = 0; ni < 4; ++ni) {
        int gcol = bn * 128 + wn + ni * 16 + lcol;
        float gv = g[(size_t)grow * 256 + gcol];
        v += gv * (acc[mi][ni][r] + wbv[gcol]);
      }
      v += __shfl_xor(v, 1); v += __shfl_xor(v, 2);
      v += __shfl_xor(v, 4); v += __shfl_xor(v, 8);
      if (lcol == 0)
        atomicAdd(&z_sq[grow], v + ((bn == 0 && wn == 0) ? bsq : 0.f));
    }
}

// ---------- min + margin-threshold candidates + exact fp32 refine + loss ----------
__global__ __launch_bounds__(256) void refine_kernel(
    const unsigned short* __restrict__ scores, const float* __restrict__ g,
    const float* __restrict__ prow, const float* __restrict__ e_sq,
    const float* __restrict__ qv, const float* __restrict__ z_sq,
    int* __restrict__ idxout, float* __restrict__ fidx,
    float* __restrict__ loss_slots) {
  const int t = threadIdx.x, l = t & 63, w = t >> 6;
  const int r = blockIdx.x * 4 + w;
  const unsigned short* srow = scores + (size_t)r * 1024;
  uint4 q0 = *(const uint4*)(srow + l * 16);
  uint4 q1 = *(const uint4*)(srow + l * 16 + 8);
  float f[16];
  {
    unsigned uu[8] = {q0.x, q0.y, q0.z, q0.w, q1.x, q1.y, q1.z, q1.w};
#pragma unroll
    for (int j = 0; j < 8; ++j) {
      f[2 * j] = __uint_as_float(uu[j] << 16);
      f[2 * j + 1] = __uint_as_float(uu[j] & 0xFFFF0000u);
    }
  }
  float mn = f[0];
#pragma unroll
  for (int j = 1; j < 16; ++j) mn = fminf(mn, f[j]);
  for (int m = 32; m; m >>= 1) mn = fminf(mn, __shfl_xor(mn, m));
  const float T = mn + 8.0f;

  float gv[4];
  const float* gr = g + (size_t)r * 256;
#pragma unroll
  for (int j = 0; j < 4; ++j) gv[j] = gr[l + 64 * j];

  float bestd = 1e30f; int bestk = 0x7fffffff;
#pragma unroll 1
  for (int j = 0; j < 16; ++j) {
    unsigned long long msk = __ballot(f[j] <= T);
    while (msk) {
      int src = __ffsll(msk) - 1;
      msk &= msk - 1;
      int k = src * 16 + j;
      const float* pr = prow + (size_t)k * 256;
      float p = 0.f;
#pragma unroll
      for (int jj = 0; jj < 4; ++jj) p += gv[jj] * pr[l + 64 * jj];
      for (int m = 32; m; m >>= 1) p += __shfl_xor(p, m);
      float d = e_sq[k] - 2.0f * (p + qv[k]);
      if (d < bestd || (d == bestd && k < bestk)) { bestd = d; bestk = k; }
    }
  }
  if (l == 0) {
    idxout[r] = bestk;
    fidx[r] = (float)bestk;
    atomicAdd(&loss_slots[r & 2047], z_sq[r] + bestd);
  }
}

// ---------- G2: quantized = embed[idx] @ post_w + post_b. M=32768 N=256 K=1024 ----------
__global__ __launch_bounds__(256) void g2_kernel(
    const unsigned short* __restrict__ embedbf,  // [1024][1024]
    const unsigned short* __restrict__ pwtbf,    // [256][1024]
    const int* __restrict__ idx, const float* __restrict__ post_b,
    float* __restrict__ out) {
  __shared__ unsigned short lds[2][16384];
  const int t = threadIdx.x;
  const int bn = blockIdx.x;  // 0..1
  const int bm = blockIdx.y;  // 0..255
  const int m0 = bm * 128;
  const int w = t >> 6, l = t & 63;
  const int wm = (w >> 1) * 64, wn = (w & 1) * 64;
  const int rbase = t >> 3;
  const int sp_st = (t & 7) ^ (rbase & 7);
  size_t arow[4];
#pragma unroll
  for (int i = 0; i < 4; ++i)
    arow[i] = (size_t)idx[m0 + rbase + 32 * i] * 1024;
  f32x4 acc[4][4] = {};
#define G2_STAGE(buf, kt)                                                       \
  do {                                                                          \
    const int k0_ = (kt) * 64;                                                  \
    unsigned short* Ab_ = &lds[buf][0];                                         \
    unsigned short* Bb_ = &lds[buf][8192];                                      \
    _Pragma("unroll")                                                           \
    for (int i = 0; i < 4; ++i) {                                               \
      int ca = t + 256 * i;                                                     \
      int rr = rbase + 32 * i;                                                  \
      gload_lds16(embedbf + arow[i] + k0_ + sp_st * 8, (char*)Ab_ + ca * 16);   \
      gload_lds16(pwtbf + (size_t)(bn * 128 + rr) * 1024 + k0_ + sp_st * 8,     \
                  (char*)Bb_ + ca * 16);                                        \
    }                                                                           \
  } while (0)
  PIPE_LOOP(16, G2_STAGE)
#undef G2_STAGE
  const int lrow = (l >> 4) * 4, lcol = l & 15;
#pragma unroll
  for (int mi = 0; mi < 4; ++mi)
#pragma unroll
    for (int ni = 0; ni < 4; ++ni) {
      int gcol = bn * 128 + wn + ni * 16 + lcol;
      float pb = post_b[gcol];
#pragma unroll
      for (int r = 0; r < 4; ++r) {
        int grow = m0 + wm + mi * 16 + lrow + r;
        out[(size_t)grow * 256 + gcol] = acc[mi][ni][r] + pb;
      }
    }
}

// ---------- loss finalize ----------
__global__ __launch_bounds__(256) void loss_final_kernel(
    const float* __restrict__ slots, float* __restrict__ out_loss) {
  float s = 0.f;
  for (int i = threadIdx.x; i < 2048; i += 256) s += slots[i];
  for (int m = 32; m; m >>= 1) s += __shfl_xor(s, m);
  __shared__ float ws_[4];
  if ((threadIdx.x & 63) == 0) ws_[threadIdx.x >> 6] = s;
  __syncthreads();
  if (threadIdx.x == 0)
    out_loss[0] = 1.25f * (ws_[0] + ws_[1] + ws_[2] + ws_[3]) / 33554432.0f;
}

extern "C" void kernel_launch(void* const* d_in, const int* in_sizes, int n_in,
                              void* d_out, int out_size, void* d_ws, size_t ws_size,
                              hipStream_t stream) {
  const float* x = (const float*)d_in[0];
  const float* ln_g = (const float*)d_in[1];
  const float* ln_b = (const float*)d_in[2];
  const float* pre_w = (const float*)d_in[3];
  const float* pre_b = (const float*)d_in[4];
  const float* embed = (const float*)d_in[5];
  const float* post_w = (const float*)d_in[6];
  const float* post_b = (const float*)d_in[7];
  float* out_q = (float*)d_out;
  float* out_idx = out_q + 8388608;
  float* out_loss = out_q + 8421376;

  char* ws = (char*)d_ws;
  size_t off = 0;
  auto alloc = [&](size_t n) { char* p = ws + off; off += (n + 255) & ~(size_t)255; return p; };
  float* g_f32 = (float*)alloc(33554432);
  unsigned short* g_bf = (unsigned short*)alloc(16777216);
  unsigned short* scores = (unsigned short*)alloc(67108864);
  float* prow = (float*)alloc(1048576);
  unsigned short* prowbf = (unsigned short*)alloc(524288);
  unsigned short* pwtbf = (unsigned short*)alloc(524288);
  unsigned short* embedbf = (unsigned short*)alloc(2097152);
  unsigned short* qbf = (unsigned short*)alloc(131072);
  float* wbv = (float*)alloc(2048);
  float* e_sq = (float*)alloc(4096);
  float* qv = (float*)alloc(4096);
  float* c0 = (float*)alloc(4096);
  float* z_sq = (float*)alloc(131072);
  int* idxw = (int*)alloc(131072);
  float* slots = (float*)alloc(8192);
  (void)ws_size; (void)in_sizes; (void)n_in; (void)out_size;

  hipMemsetAsync(z_sq, 0, 131072, stream);
  hipMemsetAsync(slots, 0, 8192, stream);

  prep_convert_kernel<<<5120, 256, 0, stream>>>(embed, post_w, embedbf, pwtbf);
  esq_kernel<<<256, 256, 0, stream>>>(embed, pre_b, e_sq, qv, c0);
  pgemm_kernel<<<512, 256, 0, stream>>>(embed, pre_w, prow, prowbf);
  qmat_kernel<<<65, 256, 0, stream>>>(pre_w, pre_b, qbf, wbv);
  lngelu_kernel<<<8192, 256, 0, stream>>>(x, ln_g, ln_b, g_f32, g_bf);
  dim3 g1grid(8, 256);
  g1_kernel<<<g1grid, 256, 0, stream>>>(g_bf, prowbf, c0, scores);
  dim3 zqgrid(2, 256);
  zq_kernel<<<zqgrid, 256, 0, stream>>>(g_bf, qbf, g_f32, wbv, z_sq);
  refine_kernel<<<8192, 256, 0, stream>>>(scores, g_f32, prow, e_sq, qv, z_sq, idxw, out_idx, slots);
  dim3 g2grid(2, 256);
  g2_kernel<<<g2grid, 256, 0, stream>>>(embedbf, pwtbf, idxw, post_b, out_q);
  loss_final_kernel<<<1, 256, 0, stream>>>(slots, out_loss);
}

// Round 8
// 196.634 us; speedup vs baseline: 1.1729x; 1.1729x over previous
//
#include <hip/hip_runtime.h>
#include <math.h>

// ---------- types / helpers ----------
typedef __attribute__((ext_vector_type(8))) short short8;
typedef __attribute__((ext_vector_type(4))) float f32x4;

__device__ __forceinline__ unsigned short f2bf(float f) {
  unsigned u = __float_as_uint(f);
  unsigned r = (u + 0x7FFFu + ((u >> 16) & 1u)) >> 16;
  return (unsigned short)r;
}

__device__ __forceinline__ void gload_lds16(const void* gsrc, void* ldst) {
  __builtin_amdgcn_global_load_lds(
      (__attribute__((address_space(1))) void*)(void*)(size_t)(const char*)gsrc,
      (__attribute__((address_space(3))) void*)ldst, 16, 0, 0);
}

// ---------- prep: bf16 converts (embed, post_w^T) ----------
__global__ __launch_bounds__(256) void prep_convert_kernel(
    const float* __restrict__ embed, const float* __restrict__ post_w,
    unsigned short* __restrict__ embedbf, unsigned short* __restrict__ pwtbf) {
  int id = blockIdx.x * 256 + threadIdx.x;
  if (id < 1048576) {
    embedbf[id] = f2bf(embed[id]);
  } else {
    int i = id - 1048576;   // pwt[j][d] = post_w[d][j]
    int j = i >> 10, dd = i & 1023;
    pwtbf[i] = f2bf(post_w[dd * 256 + j]);
  }
}

// ---------- wtf[c][d] = pre_w[d][c]  (64x64 LDS tile transpose) ----------
__global__ __launch_bounds__(256) void wtrans_kernel(
    const float* __restrict__ pre_w, float* __restrict__ wtf) {
  __shared__ float tile[64][65];
  const int bc = blockIdx.x;  // c-tile 0..15
  const int bd = blockIdx.y;  // d-tile 0..3
  const int t = threadIdx.x;
  const int col = t & 63, rr = t >> 6;
#pragma unroll
  for (int i = 0; i < 16; ++i) {
    int row = rr + i * 4;  // d within tile
    tile[row][col] = pre_w[(size_t)(bd * 64 + row) * 1024 + bc * 64 + col];
  }
  __syncthreads();
#pragma unroll
  for (int i = 0; i < 16; ++i) {
    int row = rr + i * 4;  // c within tile
    wtf[(size_t)(bc * 64 + row) * 256 + bd * 64 + col] = tile[col][row];
  }
}

// ---------- e_sq[k], q[k]=pre_b.e_k, c0[k] ----------
__global__ __launch_bounds__(256) void esq_kernel(
    const float* __restrict__ embed, const float* __restrict__ pre_b,
    float* __restrict__ e_sq, float* __restrict__ qv, float* __restrict__ c0) {
  int t = threadIdx.x, l = t & 63, w = t >> 6;
  int k = blockIdx.x * 4 + w;
  const float* er = embed + (size_t)k * 1024;
  float s1 = 0.f, s2 = 0.f;
#pragma unroll
  for (int j = 0; j < 16; ++j) {
    float e = er[l + 64 * j];
    s1 += e * e;
    s2 += pre_b[l + 64 * j] * e;
  }
  for (int m = 32; m; m >>= 1) { s1 += __shfl_xor(s1, m); s2 += __shfl_xor(s2, m); }
  if (l == 0) { e_sq[k] = s1; qv[k] = s2; c0[k] = s1 - 2.0f * s2 - 1024.0f; }
}

// ---------- P[k][d] = sum_c embed[k,c] * wtf[c,d]  (coalesced, fp64 accum) ----------
__global__ __launch_bounds__(512) void pgemm_kernel(
    const float* __restrict__ embed, const float* __restrict__ wtf,
    float* __restrict__ prow, unsigned short* __restrict__ prowbf) {
  __shared__ float Es[4096];
  __shared__ double Ps[1024];
  const int t = threadIdx.x;
  const int k0 = blockIdx.x * 4;
  *(float4*)(Es + t * 8) = *(const float4*)(embed + (size_t)k0 * 1024 + t * 8);
  *(float4*)(Es + t * 8 + 4) = *(const float4*)(embed + (size_t)k0 * 1024 + t * 8 + 4);
  __syncthreads();
  const int half = t >> 8, tl = t & 255;
  const int cbase = half * 512;
  double a0 = 0, a1 = 0, a2 = 0, a3 = 0;
  const float* wp = wtf + (size_t)cbase * 256 + tl;
#pragma unroll 4
  for (int cc = 0; cc < 512; ++cc) {
    double wv = (double)wp[(size_t)cc * 256];
    int c = cbase + cc;
    a0 += wv * (double)Es[c];
    a1 += wv * (double)Es[1024 + c];
    a2 += wv * (double)Es[2048 + c];
    a3 += wv * (double)Es[3072 + c];
  }
  if (half == 0) {
    Ps[tl] = a0; Ps[256 + tl] = a1; Ps[512 + tl] = a2; Ps[768 + tl] = a3;
  }
  __syncthreads();
  if (half == 1) {
    float p0 = (float)(a0 + Ps[tl]);
    float p1 = (float)(a1 + Ps[256 + tl]);
    float p2 = (float)(a2 + Ps[512 + tl]);
    float p3 = (float)(a3 + Ps[768 + tl]);
    prow[(size_t)k0 * 256 + tl] = p0;
    prow[(size_t)(k0 + 1) * 256 + tl] = p1;
    prow[(size_t)(k0 + 2) * 256 + tl] = p2;
    prow[(size_t)(k0 + 3) * 256 + tl] = p3;
    prowbf[(size_t)k0 * 256 + tl] = f2bf(p0);
    prowbf[(size_t)(k0 + 1) * 256 + tl] = f2bf(p1);
    prowbf[(size_t)(k0 + 2) * 256 + tl] = f2bf(p2);
    prowbf[(size_t)(k0 + 3) * 256 + tl] = f2bf(p3);
  }
}

// ---------- Q[a][d] = sum_c pre_w[a,c]*wtf[c,d] (bf16 out); wbv = {2*W.b, ||b||^2} ----------
__global__ __launch_bounds__(512) void qmat_kernel(
    const float* __restrict__ pre_w, const float* __restrict__ wtf,
    const float* __restrict__ pre_b,
    unsigned short* __restrict__ qbf, float* __restrict__ wbv) {
  __shared__ float As[4096];
  __shared__ float Ps[1024];
  const int t = threadIdx.x;
  const int half = t >> 8, tl = t & 255;
  if (blockIdx.x < 64) {
    const int a0i = blockIdx.x * 4;
    *(float4*)(As + t * 8) = *(const float4*)(pre_w + (size_t)a0i * 1024 + t * 8);
    *(float4*)(As + t * 8 + 4) = *(const float4*)(pre_w + (size_t)a0i * 1024 + t * 8 + 4);
    __syncthreads();
    const int cbase = half * 512;
    float a0 = 0.f, a1 = 0.f, a2 = 0.f, a3 = 0.f;
    const float* wp = wtf + (size_t)cbase * 256 + tl;
#pragma unroll 4
    for (int cc = 0; cc < 512; ++cc) {
      float wv = wp[(size_t)cc * 256];
      int c = cbase + cc;
      a0 += wv * As[c];
      a1 += wv * As[1024 + c];
      a2 += wv * As[2048 + c];
      a3 += wv * As[3072 + c];
    }
    if (half == 0) {
      Ps[tl] = a0; Ps[256 + tl] = a1; Ps[512 + tl] = a2; Ps[768 + tl] = a3;
    }
    __syncthreads();
    if (half == 1) {
      qbf[(size_t)a0i * 256 + tl] = f2bf(a0 + Ps[tl]);
      qbf[(size_t)(a0i + 1) * 256 + tl] = f2bf(a1 + Ps[256 + tl]);
      qbf[(size_t)(a0i + 2) * 256 + tl] = f2bf(a2 + Ps[512 + tl]);
      qbf[(size_t)(a0i + 3) * 256 + tl] = f2bf(a3 + Ps[768 + tl]);
    }
  } else {
    float s = 0.f;
    const float* wp = wtf + (size_t)(half * 512) * 256 + tl;
#pragma unroll 8
    for (int cc = 0; cc < 512; ++cc) s += wp[(size_t)cc * 256] * pre_b[half * 512 + cc];
    Ps[t] = s;
    float sb = 0.f;
    if (t < 256) {
      float4 bv = *(const float4*)(pre_b + t * 4);
      sb = bv.x * bv.x + bv.y * bv.y + bv.z * bv.z + bv.w * bv.w;
    }
    for (int m = 32; m; m >>= 1) sb += __shfl_xor(sb, m);
    if ((t & 63) == 0 && t < 256) As[t >> 6] = sb;
    __syncthreads();
    if (half == 0) wbv[tl] = 2.f * (Ps[tl] + Ps[256 + tl]);
    if (t == 0) wbv[256] = As[0] + As[1] + As[2] + As[3];
  }
}

// ---------- LN + GELU: g (f32) and g (bf16) ----------
__global__ __launch_bounds__(256) void lngelu_kernel(
    const float* __restrict__ x, const float* __restrict__ gamma,
    const float* __restrict__ beta, float* __restrict__ g,
    unsigned short* __restrict__ gbf) {
  int t = threadIdx.x, l = t & 63, w = t >> 6;
  int r = blockIdx.x * 4 + w;
  const float4 xv = *(const float4*)(x + (size_t)r * 256 + l * 4);
  float s = xv.x + xv.y + xv.z + xv.w;
  for (int m = 32; m; m >>= 1) s += __shfl_xor(s, m);
  const float mu = s * (1.0f / 256.0f);
  float dx = xv.x - mu, dy = xv.y - mu, dz = xv.z - mu, dw = xv.w - mu;
  float vs = dx * dx + dy * dy + dz * dz + dw * dw;
  for (int m = 32; m; m >>= 1) vs += __shfl_xor(vs, m);
  const float rstd = rsqrtf(vs * (1.0f / 256.0f) + 1e-5f);
  float4 gm = *(const float4*)(gamma + l * 4);
  float4 bt = *(const float4*)(beta + l * 4);
  float v0 = dx * rstd * gm.x + bt.x;
  float v1 = dy * rstd * gm.y + bt.y;
  float v2 = dz * rstd * gm.z + bt.z;
  float v3 = dw * rstd * gm.w + bt.w;
  const float is2 = 0.70710678118654752f;
  float4 o;
  o.x = 0.5f * v0 * (1.0f + erff(v0 * is2));
  o.y = 0.5f * v1 * (1.0f + erff(v1 * is2));
  o.z = 0.5f * v2 * (1.0f + erff(v2 * is2));
  o.w = 0.5f * v3 * (1.0f + erff(v3 * is2));
  *(float4*)(g + (size_t)r * 256 + l * 4) = o;
  ushort4 u;
  u.x = f2bf(o.x); u.y = f2bf(o.y); u.z = f2bf(o.z); u.w = f2bf(o.w);
  *(ushort4*)(gbf + (size_t)r * 256 + l * 4) = u;
}

// Swizzled stage: linear LDS dest (gload_lds requirement); global SOURCE slot
// XOR-permuted; read side applies the same XOR. Bank-conflict-free ds_read.
__device__ __forceinline__ void stage_tile256(
    int t, const unsigned short* __restrict__ Asrc, size_t a_row_stride,
    const unsigned short* __restrict__ Bsrc, size_t b_row_stride, int k0,
    unsigned short* Ab, unsigned short* Bb) {
#pragma unroll
  for (int i = 0; i < 4; ++i) {
    int ca = t + 256 * i;
    int r = ca >> 3;
    int sp = (ca & 7) ^ (r & 7);
    gload_lds16(Asrc + (size_t)r * a_row_stride + k0 + sp * 8, (char*)Ab + ca * 16);
    gload_lds16(Bsrc + (size_t)r * b_row_stride + k0 + sp * 8, (char*)Bb + ca * 16);
  }
}

// Proven schedule (passed full harness at bench 4): issue stage(next tile)
// BEFORE compute(cur); one __syncthreads (full drain) per K-step.
#define SAFE_LOOP_BODY(cur)                                                    \
    const unsigned short* Ab = &lds[cur][0];                                   \
    const unsigned short* Bb = &lds[cur][8192];                                \
    _Pragma("unroll")                                                          \
    for (int ks = 0; ks < 2; ++ks) {                                           \
      const int sp = ((ks << 2) + (l >> 4)) ^ (l & 7);                         \
      short8 af[4], bq[4];                                                     \
      _Pragma("unroll")                                                        \
      for (int mi = 0; mi < 4; ++mi)                                           \
        af[mi] = *(const short8*)(Ab + (wm + mi * 16 + (l & 15)) * 64 + sp * 8); \
      _Pragma("unroll")                                                        \
      for (int ni = 0; ni < 4; ++ni)                                           \
        bq[ni] = *(const short8*)(Bb + (wn + ni * 16 + (l & 15)) * 64 + sp * 8); \
      _Pragma("unroll")                                                        \
      for (int mi = 0; mi < 4; ++mi)                                           \
        _Pragma("unroll")                                                      \
        for (int ni = 0; ni < 4; ++ni)                                         \
          acc[mi][ni] = __builtin_amdgcn_mfma_f32_16x16x32_bf16(af[mi], bq[ni], acc[mi][ni], 0, 0, 0); \
    }

// ---------- G1: scores only. M=32768 N=1024 K=256 ----------
__global__ __launch_bounds__(256) void g1_kernel(
    const unsigned short* __restrict__ gbf,     // [32768][256]
    const unsigned short* __restrict__ prowbf,  // [1024][256]
    const float* __restrict__ c0,
    unsigned short* __restrict__ scores) {      // [32768][1024]
  __shared__ unsigned short lds[2][16384];
  const int t = threadIdx.x;
  const int bn = blockIdx.x;   // 0..7
  const int bm = blockIdx.y;   // 0..255
  const int m0 = bm * 128;
  const unsigned short* Bsrc = prowbf + bn * 128 * 256;
  f32x4 acc[4][4] = {};
  const int w = t >> 6, l = t & 63;
  const int wm = (w >> 1) * 64, wn = (w & 1) * 64;

  stage_tile256(t, gbf + (size_t)m0 * 256, 256, Bsrc, 256, 0, &lds[0][0], &lds[0][8192]);
  __syncthreads();
  for (int kt = 0; kt < 4; ++kt) {
    const int cur = kt & 1;
    if (kt < 3)
      stage_tile256(t, gbf + (size_t)m0 * 256, 256, Bsrc, 256, (kt + 1) * 64,
                    &lds[cur ^ 1][0], &lds[cur ^ 1][8192]);
    SAFE_LOOP_BODY(cur)
    __syncthreads();
  }
  const int lrow = (l >> 4) * 4;
  const int lcol = l & 15;
  const int n0 = bn * 128;
#pragma unroll
  for (int mi = 0; mi < 4; ++mi)
#pragma unroll
    for (int ni = 0; ni < 4; ++ni) {
      int gcol = n0 + wn + ni * 16 + lcol;
      float cc = c0[gcol];
#pragma unroll
      for (int r = 0; r < 4; ++r) {
        int grow = m0 + wm + mi * 16 + lrow + r;
        scores[(size_t)grow * 1024 + gcol] = f2bf(cc - 2.0f * acc[mi][ni][r]);
      }
    }
}

// ---------- ZQ: z_sq via Q. gQ = G@Q (M=32768 N=256 K=256), z_sq=rowsum(gQ*G)+2g.wb+bsq ----------
__global__ __launch_bounds__(256) void zq_kernel(
    const unsigned short* __restrict__ gbf, const unsigned short* __restrict__ qbf,
    const float* __restrict__ g, const float* __restrict__ wbv,
    float* __restrict__ z_sq) {
  __shared__ unsigned short lds[2][16384];
  const int t = threadIdx.x;
  const int bn = blockIdx.x;  // 0..1
  const int bm = blockIdx.y;  // 0..255
  const int m0 = bm * 128;
  const unsigned short* Bsrc = qbf + bn * 128 * 256;
  f32x4 acc[4][4] = {};
  const int w = t >> 6, l = t & 63;
  const int wm = (w >> 1) * 64, wn = (w & 1) * 64;

  stage_tile256(t, gbf + (size_t)m0 * 256, 256, Bsrc, 256, 0, &lds[0][0], &lds[0][8192]);
  __syncthreads();
  for (int kt = 0; kt < 4; ++kt) {
    const int cur = kt & 1;
    if (kt < 3)
      stage_tile256(t, gbf + (size_t)m0 * 256, 256, Bsrc, 256, (kt + 1) * 64,
                    &lds[cur ^ 1][0], &lds[cur ^ 1][8192]);
    SAFE_LOOP_BODY(cur)
    __syncthreads();
  }
  const int lrow = (l >> 4) * 4;
  const int lcol = l & 15;
  const float bsq = wbv[256];
#pragma unroll
  for (int mi = 0; mi < 4; ++mi)
#pragma unroll
    for (int r = 0; r < 4; ++r) {
      int grow = m0 + wm + mi * 16 + lrow + r;
      float v = 0.f;
#pragma unroll
      for (int ni = 0; ni < 4; ++ni) {
        int gcol = bn * 128 + wn + ni * 16 + lcol;
        float gv = g[(size_t)grow * 256 + gcol];
        v += gv * (acc[mi][ni][r] + wbv[gcol]);
      }
      v += __shfl_xor(v, 1); v += __shfl_xor(v, 2);
      v += __shfl_xor(v, 4); v += __shfl_xor(v, 8);
      if (lcol == 0)
        atomicAdd(&z_sq[grow], v + ((bn == 0 && wn == 0) ? bsq : 0.f));
    }
}

// ---------- min + margin-threshold candidates + exact fp32 refine + loss ----------
__global__ __launch_bounds__(256) void refine_kernel(
    const unsigned short* __restrict__ scores, const float* __restrict__ g,
    const float* __restrict__ prow, const float* __restrict__ e_sq,
    const float* __restrict__ qv, const float* __restrict__ z_sq,
    int* __restrict__ idxout, float* __restrict__ fidx,
    float* __restrict__ loss_slots) {
  const int t = threadIdx.x, l = t & 63, w = t >> 6;
  const int r = blockIdx.x * 4 + w;
  const unsigned short* srow = scores + (size_t)r * 1024;
  uint4 q0 = *(const uint4*)(srow + l * 16);
  uint4 q1 = *(const uint4*)(srow + l * 16 + 8);
  float f[16];
  {
    unsigned uu[8] = {q0.x, q0.y, q0.z, q0.w, q1.x, q1.y, q1.z, q1.w};
#pragma unroll
    for (int j = 0; j < 8; ++j) {
      f[2 * j] = __uint_as_float(uu[j] << 16);
      f[2 * j + 1] = __uint_as_float(uu[j] & 0xFFFF0000u);
    }
  }
  float mn = f[0];
#pragma unroll
  for (int j = 1; j < 16; ++j) mn = fminf(mn, f[j]);
  for (int m = 32; m; m >>= 1) mn = fminf(mn, __shfl_xor(mn, m));
  const float T = mn + 8.0f;

  float gv[4];
  const float* gr = g + (size_t)r * 256;
#pragma unroll
  for (int j = 0; j < 4; ++j) gv[j] = gr[l + 64 * j];

  float bestd = 1e30f; int bestk = 0x7fffffff;
#pragma unroll 1
  for (int j = 0; j < 16; ++j) {
    unsigned long long msk = __ballot(f[j] <= T);
    while (msk) {
      int src = __ffsll(msk) - 1;
      msk &= msk - 1;
      int k = src * 16 + j;
      const float* pr = prow + (size_t)k * 256;
      float p = 0.f;
#pragma unroll
      for (int jj = 0; jj < 4; ++jj) p += gv[jj] * pr[l + 64 * jj];
      for (int m = 32; m; m >>= 1) p += __shfl_xor(p, m);
      float d = e_sq[k] - 2.0f * (p + qv[k]);
      if (d < bestd || (d == bestd && k < bestk)) { bestd = d; bestk = k; }
    }
  }
  if (l == 0) {
    idxout[r] = bestk;
    fidx[r] = (float)bestk;
    atomicAdd(&loss_slots[r & 2047], z_sq[r] + bestd);
  }
}

// ---------- G2: quantized = embed[idx] @ post_w + post_b. M=32768 N=256 K=1024 ----------
__global__ __launch_bounds__(256) void g2_kernel(
    const unsigned short* __restrict__ embedbf,  // [1024][1024]
    const unsigned short* __restrict__ pwtbf,    // [256][1024]
    const int* __restrict__ idx, const float* __restrict__ post_b,
    float* __restrict__ out) {
  __shared__ unsigned short lds[2][16384];
  const int t = threadIdx.x;
  const int bn = blockIdx.x;  // 0..1
  const int bm = blockIdx.y;  // 0..255
  const int m0 = bm * 128;
  const int w = t >> 6, l = t & 63;
  const int wm = (w >> 1) * 64, wn = (w & 1) * 64;
  const int rbase = t >> 3;
  const int sp_st = (t & 7) ^ (rbase & 7);
  size_t arow[4];
#pragma unroll
  for (int i = 0; i < 4; ++i)
    arow[i] = (size_t)idx[m0 + rbase + 32 * i] * 1024;
  f32x4 acc[4][4] = {};
  auto stage = [&](int buf, int kt) {
    const int k0 = kt * 64;
    unsigned short* Ab = &lds[buf][0];
    unsigned short* Bb = &lds[buf][8192];
#pragma unroll
    for (int i = 0; i < 4; ++i) {
      int ca = t + 256 * i;
      int rr = rbase + 32 * i;
      gload_lds16(embedbf + arow[i] + k0 + sp_st * 8, (char*)Ab + ca * 16);
      gload_lds16(pwtbf + (size_t)(bn * 128 + rr) * 1024 + k0 + sp_st * 8,
                  (char*)Bb + ca * 16);
    }
  };
  stage(0, 0);
  __syncthreads();
  for (int kt = 0; kt < 16; ++kt) {
    const int cur = kt & 1;
    if (kt < 15) stage(cur ^ 1, kt + 1);
    SAFE_LOOP_BODY(cur)
    __syncthreads();
  }
  const int lrow = (l >> 4) * 4, lcol = l & 15;
#pragma unroll
  for (int mi = 0; mi < 4; ++mi)
#pragma unroll
    for (int ni = 0; ni < 4; ++ni) {
      int gcol = bn * 128 + wn + ni * 16 + lcol;
      float pb = post_b[gcol];
#pragma unroll
      for (int r = 0; r < 4; ++r) {
        int grow = m0 + wm + mi * 16 + lrow + r;
        out[(size_t)grow * 256 + gcol] = acc[mi][ni][r] + pb;
      }
    }
}

// ---------- loss finalize ----------
__global__ __launch_bounds__(256) void loss_final_kernel(
    const float* __restrict__ slots, float* __restrict__ out_loss) {
  float s = 0.f;
  for (int i = threadIdx.x; i < 2048; i += 256) s += slots[i];
  for (int m = 32; m; m >>= 1) s += __shfl_xor(s, m);
  __shared__ float ws_[4];
  if ((threadIdx.x & 63) == 0) ws_[threadIdx.x >> 6] = s;
  __syncthreads();
  if (threadIdx.x == 0)
    out_loss[0] = 1.25f * (ws_[0] + ws_[1] + ws_[2] + ws_[3]) / 33554432.0f;
}

extern "C" void kernel_launch(void* const* d_in, const int* in_sizes, int n_in,
                              void* d_out, int out_size, void* d_ws, size_t ws_size,
                              hipStream_t stream) {
  const float* x = (const float*)d_in[0];
  const float* ln_g = (const float*)d_in[1];
  const float* ln_b = (const float*)d_in[2];
  const float* pre_w = (const float*)d_in[3];
  const float* pre_b = (const float*)d_in[4];
  const float* embed = (const float*)d_in[5];
  const float* post_w = (const float*)d_in[6];
  const float* post_b = (const float*)d_in[7];
  float* out_q = (float*)d_out;
  float* out_idx = out_q + 8388608;
  float* out_loss = out_q + 8421376;

  char* ws = (char*)d_ws;
  size_t off = 0;
  auto alloc = [&](size_t n) { char* p = ws + off; off += (n + 255) & ~(size_t)255; return p; };
  float* g_f32 = (float*)alloc(33554432);
  unsigned short* g_bf = (unsigned short*)alloc(16777216);
  unsigned short* scores = (unsigned short*)alloc(67108864);
  float* prow = (float*)alloc(1048576);
  unsigned short* prowbf = (unsigned short*)alloc(524288);
  unsigned short* pwtbf = (unsigned short*)alloc(524288);
  unsigned short* embedbf = (unsigned short*)alloc(2097152);
  unsigned short* qbf = (unsigned short*)alloc(131072);
  float* wtf = (float*)alloc(1048576);
  float* wbv = (float*)alloc(2048);
  float* e_sq = (float*)alloc(4096);
  float* qv = (float*)alloc(4096);
  float* c0 = (float*)alloc(4096);
  float* z_sq = (float*)alloc(131072);
  int* idxw = (int*)alloc(131072);
  float* slots = (float*)alloc(8192);
  (void)ws_size; (void)in_sizes; (void)n_in; (void)out_size;

  hipMemsetAsync(z_sq, 0, 131072, stream);
  hipMemsetAsync(slots, 0, 8192, stream);

  prep_convert_kernel<<<5120, 256, 0, stream>>>(embed, post_w, embedbf, pwtbf);
  dim3 wtg(16, 4);
  wtrans_kernel<<<wtg, 256, 0, stream>>>(pre_w, wtf);
  esq_kernel<<<256, 256, 0, stream>>>(embed, pre_b, e_sq, qv, c0);
  pgemm_kernel<<<256, 512, 0, stream>>>(embed, wtf, prow, prowbf);
  qmat_kernel<<<65, 512, 0, stream>>>(pre_w, wtf, pre_b, qbf, wbv);
  lngelu_kernel<<<8192, 256, 0, stream>>>(x, ln_g, ln_b, g_f32, g_bf);
  dim3 g1grid(8, 256);
  g1_kernel<<<g1grid, 256, 0, stream>>>(g_bf, prowbf, c0, scores);
  dim3 zqgrid(2, 256);
  zq_kernel<<<zqgrid, 256, 0, stream>>>(g_bf, qbf, g_f32, wbv, z_sq);
  refine_kernel<<<8192, 256, 0, stream>>>(scores, g_f32, prow, e_sq, qv, z_sq, idxw, out_idx, slots);
  dim3 g2grid(2, 256);
  g2_kernel<<<g2grid, 256, 0, stream>>>(embedbf, pwtbf, idxw, post_b, out_q);
  loss_final_kernel<<<1, 256, 0, stream>>>(slots, out_loss);
}